// Round 3
// baseline (2080.082 us; speedup 1.0000x reference)
//
#include <hip/hip_runtime.h>
#include <hip/hip_bf16.h>

typedef __hip_bfloat16 bf16;

#define N_NODES 100000
#define E_EDGES 800000

static __device__ __forceinline__ float b2f(bf16 v) { return __bfloat162float(v); }
static __device__ __forceinline__ float ldf(const float* p, size_t i) { return p[i]; }
static __device__ __forceinline__ float ldf(const bf16* p, size_t i) { return __bfloat162float(p[i]); }

// ---------------- CSR build (by destination), shared by both layers ----------------
__global__ void hist2_k(const int* __restrict__ dst0, const int* __restrict__ dst1,
                        int* deg0, int* deg1) {
  int i = blockIdx.x * 256 + threadIdx.x;
  if (i < E_EDGES) {
    atomicAdd(&deg0[dst0[i]], 1);
    atomicAdd(&deg1[dst1[i]], 1);
  }
}

// one block per relation; sequential chunked Hillis-Steele scan over N_NODES
__global__ void scan2_k(const int* __restrict__ deg0, const int* __restrict__ deg1,
                        int* rp0, int* rp1, int* fill0, int* fill1) {
  __shared__ int s[1024];
  __shared__ int s_carry;
  const int* deg = blockIdx.x ? deg1 : deg0;
  int* rp   = blockIdx.x ? rp1   : rp0;
  int* fill = blockIdx.x ? fill1 : fill0;
  int tid = threadIdx.x;
  if (tid == 0) s_carry = 0;
  __syncthreads();
  for (int base = 0; base < N_NODES; base += 1024) {
    int i = base + tid;
    int v = (i < N_NODES) ? deg[i] : 0;
    s[tid] = v;
    __syncthreads();
    for (int off = 1; off < 1024; off <<= 1) {
      int t = (tid >= off) ? s[tid - off] : 0;
      __syncthreads();
      s[tid] += t;
      __syncthreads();
    }
    int incl = s[tid];
    int excl = incl - v;
    int carry = s_carry;
    if (i < N_NODES) { rp[i] = carry + excl; fill[i] = carry + excl; }
    int total = s[1023];
    __syncthreads();
    if (tid == 0) s_carry = carry + total;
    __syncthreads();
  }
  if (tid == 0) rp[N_NODES] = s_carry;
}

__global__ void scat2_k(const int* __restrict__ dst0, const int* __restrict__ dst1,
                        int* fill0, int* fill1, int* col0, int* col1) {
  int i = blockIdx.x * 256 + threadIdx.x;
  if (i < E_EDGES) {
    int p0 = atomicAdd(&fill0[dst0[i]], 1); col0[p0] = i;
    int p1 = atomicAdd(&fill1[dst1[i]], 1); col1[p1] = i;
  }
}

// ---------------- dense transforms: xl = feat@Wl + bl, xr = feat@Wr + br ----------------
// 256 threads = 2 nodes x 128 output channels; fp32 accumulate, bf16 store
template <typename T>
__global__ void transform_k(const T* __restrict__ feat, int K,
                            const float* __restrict__ Wl, const float* __restrict__ bl,
                            const float* __restrict__ Wr, const float* __restrict__ br,
                            bf16* __restrict__ xl, bf16* __restrict__ xr) {
  __shared__ float sf[2][64];
  int li = threadIdx.x >> 7;
  int c = threadIdx.x & 127;
  int node = blockIdx.x * 2 + li;
  if (node < N_NODES && c < K) sf[li][c] = ldf(feat, (size_t)node * K + c);
  __syncthreads();
  if (node >= N_NODES) return;
  float al = bl[c];
  float ar = br[c];
  const float* f = sf[li];
  for (int k = 0; k < K; ++k) {
    float fv = f[k];
    al += fv * Wl[k * 128 + c];
    ar += fv * Wr[k * 128 + c];
  }
  size_t o = (size_t)node * 128 + c;
  xl[o] = __float2bfloat16(al);
  xr[o] = __float2bfloat16(ar);
}

// ---------------- per-edge: score -> exp, accumulate softmax denom ----------------
// one 64-lane wave per edge; lane l handles channel l (head0) and l+64 (head1).
// Scores are O(1) (0.1-scale weights): exp without max-subtraction is safe and,
// after normalization, mathematically identical (softmax shift invariance).
__global__ void edge_k(const int* __restrict__ esrc, const int* __restrict__ edst,
                       const bf16* __restrict__ xl, const bf16* __restrict__ xr,
                       const float* __restrict__ att,
                       float* __restrict__ exbuf, float* __restrict__ denom) {
  int e = (blockIdx.x * 256 + threadIdx.x) >> 6;
  int lane = threadIdx.x & 63;
  if (e >= E_EDGES) return;
  int s = esrc[e], d = edst[e];
  const bf16* pl = xl + (size_t)s * 128;
  const bf16* pr = xr + (size_t)d * 128;
  float e0 = b2f(pl[lane]) + b2f(pr[lane]);
  float e1 = b2f(pl[lane + 64]) + b2f(pr[lane + 64]);
  e0 = (e0 > 0.f ? e0 : 0.2f * e0) * att[lane];
  e1 = (e1 > 0.f ? e1 : 0.2f * e1) * att[lane + 64];
#pragma unroll
  for (int off = 1; off < 64; off <<= 1) {
    e0 += __shfl_xor(e0, off);
    e1 += __shfl_xor(e1, off);
  }
  if (lane == 0) {
    float x0 = __expf(e0), x1 = __expf(e1);
    exbuf[(size_t)e * 2]     = x0;
    exbuf[(size_t)e * 2 + 1] = x1;
    atomicAdd(&denom[(size_t)d * 2],     x0);
    atomicAdd(&denom[(size_t)d * 2 + 1], x1);
  }
}

// ---------------- per-dst CSR aggregation + head mean + bias (+ relation mean) ----------------
// one 64-lane wave per destination node. phase 0: write fp32 partial to accum.
// phase 1: combine with accum, 0.5x relation mean, optional relu, store.
// outb (bf16) xor outf (fp32) selects the destination; outf may alias accum
// (same index, read-before-write within the thread).
__global__ void agg_k(const int* __restrict__ rp, const int* __restrict__ col,
                      const int* __restrict__ esrc,
                      const float* __restrict__ exbuf, const float* __restrict__ denom,
                      const bf16* __restrict__ xl, const float* __restrict__ bias,
                      float* __restrict__ accum, bf16* __restrict__ outb,
                      float* __restrict__ outf, int phase, int do_relu) {
  int d = (blockIdx.x * 256 + threadIdx.x) >> 6;
  int lane = threadIdx.x & 63;
  if (d >= N_NODES) return;
  int beg = rp[d], end = rp[d + 1];
  float inv0 = 1.f / (denom[(size_t)d * 2] + 1e-16f);
  float inv1 = 1.f / (denom[(size_t)d * 2 + 1] + 1e-16f);
  float acc0 = 0.f, acc1 = 0.f;
  for (int j = beg; j < end; ++j) {
    int eid = col[j];
    int s = esrc[eid];
    float a0 = exbuf[(size_t)eid * 2] * inv0;
    float a1 = exbuf[(size_t)eid * 2 + 1] * inv1;
    const bf16* pl = xl + (size_t)s * 128;
    acc0 += b2f(pl[lane]) * a0;
    acc1 += b2f(pl[lane + 64]) * a1;
  }
  float o = 0.5f * (acc0 + acc1) + bias[lane];
  size_t oi = (size_t)d * 64 + lane;
  if (phase == 0) {
    accum[oi] = o;
  } else {
    float v = 0.5f * (accum[oi] + o);
    if (do_relu) v = v > 0.f ? v : 0.f;
    if (outf) outf[oi] = v;
    else outb[oi] = __float2bfloat16(v);
  }
}

extern "C" void kernel_launch(void* const* d_in, const int* in_sizes, int n_in,
                              void* d_out, int out_size, void* d_ws, size_t ws_size,
                              hipStream_t stream) {
  const float* x       = (const float*)d_in[0];
  const int*   e_adj   = (const int*)d_in[1];
  const int*   e_ray   = (const int*)d_in[2];
  const float* l1_Wl   = (const float*)d_in[3];
  const float* l1_bl   = (const float*)d_in[4];
  const float* l1_Wr   = (const float*)d_in[5];
  const float* l1_br   = (const float*)d_in[6];
  const float* l1_att  = (const float*)d_in[7];
  const float* l1_bias = (const float*)d_in[8];
  const float* l2_Wl   = (const float*)d_in[9];
  const float* l2_bl   = (const float*)d_in[10];
  const float* l2_Wr   = (const float*)d_in[11];
  const float* l2_br   = (const float*)d_in[12];
  const float* l2_att  = (const float*)d_in[13];
  const float* l2_bias = (const float*)d_in[14];
  float* out = (float*)d_out;

  // compact workspace allocator (total ~80 MB)
  char* w = (char*)d_ws;
  size_t off = 0;
  auto alloc = [&](size_t bytes) -> char* {
    char* p = w + off;
    off += (bytes + 255) & ~(size_t)255;
    return p;
  };
  bf16* XL   = (bf16*)alloc((size_t)N_NODES * 128 * 2);   // 25.6 MB
  bf16* XR   = (bf16*)alloc((size_t)N_NODES * 128 * 2);   // 25.6 MB
  float* EX  = (float*)alloc((size_t)E_EDGES * 2 * 4);    //  6.4 MB
  float* DEN = (float*)alloc((size_t)N_NODES * 2 * 4);    //  0.8 MB
  bf16* H    = (bf16*)alloc((size_t)N_NODES * 64 * 2);    // 12.8 MB (layer-1 hidden)
  int* RP0   = (int*)alloc((size_t)(N_NODES + 1) * 4);
  int* RP1   = (int*)alloc((size_t)(N_NODES + 1) * 4);
  int* FI0   = (int*)alloc((size_t)N_NODES * 4);
  int* FI1   = (int*)alloc((size_t)N_NODES * 4);
  int* CO0   = (int*)alloc((size_t)E_EDGES * 4);          //  3.2 MB
  int* CO1   = (int*)alloc((size_t)E_EDGES * 4);          //  3.2 MB
  int* DG0   = (int*)alloc((size_t)N_NODES * 4);
  int* DG1   = (int*)alloc((size_t)N_NODES * 4);
  // relation-partial accumulator lives in d_out (fp32 N*64): phase-1 reads
  // accum[oi] before writing outf[oi] at the same index -> safe aliasing.
  float* ACC = out;

  const int* src_adj = e_adj;
  const int* dst_adj = e_adj + E_EDGES;
  const int* src_ray = e_ray;
  const int* dst_ray = e_ray + E_EDGES;

  const int EB  = (E_EDGES + 255) / 256;   // 3125
  const int WEB = (E_EDGES * 64) / 256;    // 200000 (one wave per edge)
  const int WNB = (N_NODES * 64) / 256;    // 25000  (one wave per node)
  const int TNB = (N_NODES + 1) / 2;       // 50000  (two nodes per block)

  // CSR build (reused by both layers)
  hipMemsetAsync(DG0, 0, (size_t)N_NODES * 4, stream);
  hipMemsetAsync(DG1, 0, (size_t)N_NODES * 4, stream);
  hist2_k<<<EB, 256, 0, stream>>>(dst_adj, dst_ray, DG0, DG1);
  scan2_k<<<2, 1024, 0, stream>>>(DG0, DG1, RP0, RP1, FI0, FI1);
  scat2_k<<<EB, 256, 0, stream>>>(dst_adj, dst_ray, FI0, FI1, CO0, CO1);

  // ---- layer 1 (input x fp32, K=2), relu at the end, hidden -> H (bf16) ----
  for (int r = 0; r < 2; ++r) {
    const int* src = r ? src_ray : src_adj;
    const int* dst = r ? dst_ray : dst_adj;
    const int* rp  = r ? RP1 : RP0;
    const int* co  = r ? CO1 : CO0;
    hipMemsetAsync(DEN, 0, (size_t)N_NODES * 2 * 4, stream);
    transform_k<float><<<TNB, 256, 0, stream>>>(x, 2,
        l1_Wl + r * 256, l1_bl + r * 128, l1_Wr + r * 256, l1_br + r * 128, XL, XR);
    edge_k<<<WEB, 256, 0, stream>>>(src, dst, XL, XR, l1_att + r * 128, EX, DEN);
    agg_k<<<WNB, 256, 0, stream>>>(rp, co, src, EX, DEN, XL, l1_bias + r * 64,
                                   ACC, H, nullptr, r, 1);
  }

  // ---- layer 2 (input H bf16, K=64), writes fp32 output ----
  for (int r = 0; r < 2; ++r) {
    const int* src = r ? src_ray : src_adj;
    const int* dst = r ? dst_ray : dst_adj;
    const int* rp  = r ? RP1 : RP0;
    const int* co  = r ? CO1 : CO0;
    hipMemsetAsync(DEN, 0, (size_t)N_NODES * 2 * 4, stream);
    transform_k<bf16><<<TNB, 256, 0, stream>>>(H, 64,
        l2_Wl + r * 8192, l2_bl + r * 128, l2_Wr + r * 8192, l2_br + r * 128, XL, XR);
    edge_k<<<WEB, 256, 0, stream>>>(src, dst, XL, XR, l2_att + r * 128, EX, DEN);
    agg_k<<<WNB, 256, 0, stream>>>(rp, co, src, EX, DEN, XL, l2_bias + r * 64,
                                   ACC, nullptr, out, r, 0);
  }
}

// Round 4
// 1023.713 us; speedup vs baseline: 2.0319x; 2.0319x over previous
//
#include <hip/hip_runtime.h>
#include <hip/hip_bf16.h>

typedef __hip_bfloat16 bf16;
typedef unsigned int uint;
typedef unsigned short ushort;
typedef __attribute__((ext_vector_type(8))) short short8;  // 8 x bf16 (4 VGPRs)
typedef __attribute__((ext_vector_type(4))) float floatx4;

#define N_NODES 100000
#define N_PAD   100096   // multiple of 128 for the MFMA row tiling
#define E_EDGES 800000

static __device__ __forceinline__ uint packbf(float a, float b) {
  bf16 x = __float2bfloat16(a), y = __float2bfloat16(b);
  ushort ux = *reinterpret_cast<ushort*>(&x);
  ushort uy = *reinterpret_cast<ushort*>(&y);
  return (uint)ux | ((uint)uy << 16);
}

// ---------------- CSR build (by destination), shared by both layers ----------------
__global__ void hist2_k(const int* __restrict__ dst0, const int* __restrict__ dst1,
                        int* deg0, int* deg1) {
  int i = blockIdx.x * 256 + threadIdx.x;
  if (i < E_EDGES) {
    atomicAdd(&deg0[dst0[i]], 1);
    atomicAdd(&deg1[dst1[i]], 1);
  }
}

__global__ void scan2_k(const int* __restrict__ deg0, const int* __restrict__ deg1,
                        int* rp0, int* rp1, int* fill0, int* fill1) {
  __shared__ int s[1024];
  __shared__ int s_carry;
  const int* deg = blockIdx.x ? deg1 : deg0;
  int* rp   = blockIdx.x ? rp1   : rp0;
  int* fill = blockIdx.x ? fill1 : fill0;
  int tid = threadIdx.x;
  if (tid == 0) s_carry = 0;
  __syncthreads();
  for (int base = 0; base < N_NODES; base += 1024) {
    int i = base + tid;
    int v = (i < N_NODES) ? deg[i] : 0;
    s[tid] = v;
    __syncthreads();
    for (int off = 1; off < 1024; off <<= 1) {
      int t = (tid >= off) ? s[tid - off] : 0;
      __syncthreads();
      s[tid] += t;
      __syncthreads();
    }
    int incl = s[tid];
    int excl = incl - v;
    int carry = s_carry;
    if (i < N_NODES) { rp[i] = carry + excl; fill[i] = carry + excl; }
    int total = s[1023];
    __syncthreads();
    if (tid == 0) s_carry = carry + total;
    __syncthreads();
  }
  if (tid == 0) rp[N_NODES] = s_carry;
}

// col stores the SOURCE node id directly (no edge-id indirection needed anymore)
__global__ void scat2_k(const int* __restrict__ src0, const int* __restrict__ dst0,
                        const int* __restrict__ src1, const int* __restrict__ dst1,
                        int* fill0, int* fill1, int* cs0, int* cs1) {
  int i = blockIdx.x * 256 + threadIdx.x;
  if (i < E_EDGES) {
    int p0 = atomicAdd(&fill0[dst0[i]], 1); cs0[p0] = src0[i];
    int p1 = atomicAdd(&fill1[dst1[i]], 1); cs1[p1] = src1[i];
  }
}

// ---------------- layer-1 transform (K=2), scalar, writes XLR[node][256] bf16 ----------------
// thread -> (node, side l/r, channel pair); packed b32 stores
__global__ void t1_k(const float* __restrict__ x,
                     const float* __restrict__ Wl, const float* __restrict__ blp,
                     const float* __restrict__ Wr, const float* __restrict__ brp,
                     bf16* __restrict__ XLR) {
  int t = threadIdx.x;
  int node = blockIdx.x * 2 + (t >> 7);
  if (node >= N_NODES) return;
  int qq = t & 127;
  int side = qq >> 6;
  int p = qq & 63;
  int c0 = 2 * p;
  const float* W = side ? Wr : Wl;   // [2][128] k-major
  const float* B = side ? brp : blp;
  float x0 = x[node * 2], x1 = x[node * 2 + 1];
  float v0 = B[c0]     + x0 * W[c0]     + x1 * W[128 + c0];
  float v1 = B[c0 + 1] + x0 * W[c0 + 1] + x1 * W[128 + c0 + 1];
  *(uint*)(XLR + (size_t)node * 256 + side * 128 + c0) = packbf(v0, v1);
}

// ---------------- layer-2 weight prep: WT[rel][c=0..255][k=0..63] bf16 (transposed) ----------------
__global__ void wprep_k(const float* __restrict__ Wl, const float* __restrict__ Wr,
                        short* __restrict__ WT) {
  int id2 = blockIdx.x * 256 + threadIdx.x;   // 32768 = 2 rel x 256 c x 64 k
  int rel = id2 >> 14;
  int id = id2 & 16383;
  int c = id >> 6, k = id & 63;
  const float* W = (c < 128) ? (Wl + rel * 8192) : (Wr + rel * 8192);
  int cc = c & 127;
  bf16 b = __float2bfloat16(W[k * 128 + cc]);
  WT[rel * 16384 + c * 64 + k] = *reinterpret_cast<short*>(&b);
}

// ---------------- layer-2 transform: XLR[N][256] = HB[N][64] @ WT^T, MFMA 16x16x32 ----------------
// block = 256 thr (4 waves) x 128 rows; W in LDS (row pad +8 shorts -> conflict-free b128)
__global__ __launch_bounds__(256) void mfma_t_k(const bf16* __restrict__ HB,
                                                const short* __restrict__ WT,
                                                const float* __restrict__ bl,
                                                const float* __restrict__ br,
                                                bf16* __restrict__ XLR) {
  __shared__ short sW[256 * 72];
  int t = threadIdx.x;
#pragma unroll
  for (int i = 0; i < 8; ++i) {
    int chunk = t + i * 256;                 // 2048 chunks of 8 shorts
    int c = chunk >> 3, off = (chunk & 7) * 8;
    *(short8*)(&sW[c * 72 + off]) = *(const short8*)(WT + chunk * 8);
  }
  __syncthreads();
  int wave = t >> 6, lane = t & 63;
  int q = lane >> 4, m = lane & 15;
  int rowbase = blockIdx.x * 128 + wave * 32;
  // A-frags from global: A[m][k], m=lane&15, k=q*8+j (+32 for kh=1)
  short8 afr[2][2];
#pragma unroll
  for (int rt = 0; rt < 2; ++rt)
#pragma unroll
    for (int kh = 0; kh < 2; ++kh) {
      size_t row = (size_t)(rowbase + rt * 16 + m);
      afr[rt][kh] = *(const short8*)((const short*)HB + row * 64 + kh * 32 + q * 8);
    }
  for (int ct = 0; ct < 16; ++ct) {
    int col = ct * 16 + m;
    // B[k][n]: n=lane&15 -> row 'col' of WT; k=q*8+j contiguous
    short8 b0 = *(const short8*)(&sW[col * 72 + q * 8]);
    short8 b1 = *(const short8*)(&sW[col * 72 + 32 + q * 8]);
    float bias = (col < 128) ? bl[col] : br[col - 128];
#pragma unroll
    for (int rt = 0; rt < 2; ++rt) {
      floatx4 acc = {0.f, 0.f, 0.f, 0.f};
      acc = __builtin_amdgcn_mfma_f32_16x16x32_bf16(afr[rt][0], b0, acc, 0, 0, 0);
      acc = __builtin_amdgcn_mfma_f32_16x16x32_bf16(afr[rt][1], b1, acc, 0, 0, 0);
      int r0 = rowbase + rt * 16 + q * 4;    // C/D: col=lane&15, row=q*4+reg
#pragma unroll
      for (int i2 = 0; i2 < 4; ++i2) {
        int row = r0 + i2;
        if (row < N_NODES)
          XLR[(size_t)row * 256 + col] = __float2bfloat16(acc[i2] + bias);
      }
    }
  }
}

// ---------------- fused per-dst: scores + softmax + aggregation, one wave per node ----------------
// lane l owns channels {2l, 2l+1} (head = l>>5). Per edge: one b32 gather of xl[src],
// score recomputed in-register (softmax shift-invariance: no max needed, scores are O(1)).
__global__ void agg_fused_k(const int* __restrict__ rp, const int* __restrict__ colsrc,
                            const bf16* __restrict__ XLR,
                            const float* __restrict__ att, const float* __restrict__ bias,
                            float* __restrict__ accum, uint* __restrict__ houtp,
                            float* __restrict__ outf, int phase, int do_relu) {
  int d = (blockIdx.x * 256 + threadIdx.x) >> 6;
  int lane = threadIdx.x & 63;
  if (d >= N_NODES) return;
  int beg = rp[d], end = rp[d + 1];
  uint uxr = *(const uint*)(XLR + (size_t)d * 256 + 128 + 2 * lane);
  float xr0 = __uint_as_float((uxr & 0xffffu) << 16);
  float xr1 = __uint_as_float(uxr & 0xffff0000u);
  float a0 = att[2 * lane], a1 = att[2 * lane + 1];
  float acc0 = 0.f, acc1 = 0.f, den = 0.f;
  for (int j = beg; j < end; ++j) {
    int s = colsrc[j];
    uint u = *(const uint*)(XLR + (size_t)s * 256 + 2 * lane);
    float x0 = __uint_as_float((u & 0xffffu) << 16);
    float x1 = __uint_as_float(u & 0xffff0000u);
    float e0 = x0 + xr0, e1 = x1 + xr1;
    e0 = e0 > 0.f ? e0 : 0.2f * e0;
    e1 = e1 > 0.f ? e1 : 0.2f * e1;
    float p = e0 * a0 + e1 * a1;
    p += __shfl_xor(p, 1);
    p += __shfl_xor(p, 2);
    p += __shfl_xor(p, 4);
    p += __shfl_xor(p, 8);
    p += __shfl_xor(p, 16);      // each 32-half now holds its head's full score
    float ex = __expf(p);
    den += ex;
    acc0 += ex * x0;
    acc1 += ex * x1;
  }
  float inv = 1.f / (den + 1e-16f);
  acc0 *= inv; acc1 *= inv;
  float o0 = 0.5f * (acc0 + __shfl_xor(acc0, 32));   // head mean
  float o1 = 0.5f * (acc1 + __shfl_xor(acc1, 32));
  if (lane < 32) {
    int c0 = 2 * lane;
    o0 += bias[c0]; o1 += bias[c0 + 1];
    size_t oi = (size_t)d * 64 + c0;
    if (phase == 0) {
      *(float2*)(accum + oi) = make_float2(o0, o1);
    } else {
      float2 pa = *(const float2*)(accum + oi);
      float v0 = 0.5f * (pa.x + o0);
      float v1 = 0.5f * (pa.y + o1);
      if (do_relu) { v0 = fmaxf(v0, 0.f); v1 = fmaxf(v1, 0.f); }
      if (outf) *(float2*)(outf + oi) = make_float2(v0, v1);
      else houtp[oi >> 1] = packbf(v0, v1);
    }
  }
}

extern "C" void kernel_launch(void* const* d_in, const int* in_sizes, int n_in,
                              void* d_out, int out_size, void* d_ws, size_t ws_size,
                              hipStream_t stream) {
  const float* x       = (const float*)d_in[0];
  const int*   e_adj   = (const int*)d_in[1];
  const int*   e_ray   = (const int*)d_in[2];
  const float* l1_Wl   = (const float*)d_in[3];
  const float* l1_bl   = (const float*)d_in[4];
  const float* l1_Wr   = (const float*)d_in[5];
  const float* l1_br   = (const float*)d_in[6];
  const float* l1_att  = (const float*)d_in[7];
  const float* l1_bias = (const float*)d_in[8];
  const float* l2_Wl   = (const float*)d_in[9];
  const float* l2_bl   = (const float*)d_in[10];
  const float* l2_Wr   = (const float*)d_in[11];
  const float* l2_br   = (const float*)d_in[12];
  const float* l2_att  = (const float*)d_in[13];
  const float* l2_bias = (const float*)d_in[14];
  float* out = (float*)d_out;

  // workspace (~73 MB)
  char* w = (char*)d_ws;
  size_t off = 0;
  auto alloc = [&](size_t bytes) -> char* {
    char* p = w + off;
    off += (bytes + 255) & ~(size_t)255;
    return p;
  };
  bf16* XLR  = (bf16*)alloc((size_t)N_PAD * 256 * 2);   // 51.2 MB [node][xl 0..127 | xr 128..255]
  bf16* HB   = (bf16*)alloc((size_t)N_PAD * 64 * 2);    // 12.8 MB layer-1 hidden (bf16)
  short* WT  = (short*)alloc(2 * 16384 * 2);            // 64 KB layer-2 transposed weights
  int* RP0   = (int*)alloc((size_t)(N_NODES + 1) * 4);
  int* RP1   = (int*)alloc((size_t)(N_NODES + 1) * 4);
  int* FI0   = (int*)alloc((size_t)N_NODES * 4);
  int* FI1   = (int*)alloc((size_t)N_NODES * 4);
  int* CS0   = (int*)alloc((size_t)E_EDGES * 4);
  int* CS1   = (int*)alloc((size_t)E_EDGES * 4);
  int* DG0   = (int*)alloc((size_t)N_NODES * 4);
  int* DG1   = (int*)alloc((size_t)N_NODES * 4);
  float* ACC = out;  // relation-0 partial; phase-1 reads before writing same index

  const int* src_adj = e_adj;
  const int* dst_adj = e_adj + E_EDGES;
  const int* src_ray = e_ray;
  const int* dst_ray = e_ray + E_EDGES;

  const int EB  = (E_EDGES + 255) / 256;   // 3125
  const int WNB = (N_NODES * 64) / 256;    // 25000 (one wave per node)
  const int TNB = (N_NODES + 1) / 2;       // 50000
  const int MB  = N_PAD / 128;             // 782

  // CSR build (reused by both layers)
  hipMemsetAsync(DG0, 0, (size_t)N_NODES * 4, stream);
  hipMemsetAsync(DG1, 0, (size_t)N_NODES * 4, stream);
  hist2_k<<<EB, 256, 0, stream>>>(dst_adj, dst_ray, DG0, DG1);
  scan2_k<<<2, 1024, 0, stream>>>(DG0, DG1, RP0, RP1, FI0, FI1);
  scat2_k<<<EB, 256, 0, stream>>>(src_adj, dst_adj, src_ray, dst_ray, FI0, FI1, CS0, CS1);
  wprep_k<<<128, 256, 0, stream>>>(l2_Wl, l2_Wr, WT);

  // ---- layer 1 (K=2), relu, hidden -> HB (bf16) ----
  for (int r = 0; r < 2; ++r) {
    const int* rp = r ? RP1 : RP0;
    const int* cs = r ? CS1 : CS0;
    t1_k<<<TNB, 256, 0, stream>>>(x, l1_Wl + r * 256, l1_bl + r * 128,
                                  l1_Wr + r * 256, l1_br + r * 128, XLR);
    agg_fused_k<<<WNB, 256, 0, stream>>>(rp, cs, XLR, l1_att + r * 128, l1_bias + r * 64,
                                         ACC, (uint*)HB, nullptr, r, 1);
  }

  // ---- layer 2 (K=64, MFMA), writes fp32 output ----
  for (int r = 0; r < 2; ++r) {
    const int* rp = r ? RP1 : RP0;
    const int* cs = r ? CS1 : CS0;
    mfma_t_k<<<MB, 256, 0, stream>>>(HB, WT + r * 16384,
                                     l2_bl + r * 128, l2_br + r * 128, XLR);
    agg_fused_k<<<WNB, 256, 0, stream>>>(rp, cs, XLR, l2_att + r * 128, l2_bias + r * 64,
                                         ACC, nullptr, out, r, 0);
  }
}

// Round 5
// 644.470 us; speedup vs baseline: 3.2276x; 1.5885x over previous
//
#include <hip/hip_runtime.h>
#include <hip/hip_bf16.h>

typedef __hip_bfloat16 bf16;
typedef unsigned int uint;
typedef unsigned short ushort;
typedef __attribute__((ext_vector_type(8))) short short8;  // 8 x bf16 (4 VGPRs)
typedef __attribute__((ext_vector_type(4))) float floatx4;

#define N_NODES 100000
#define N_PAD   100096   // multiple of 128 for the MFMA row tiling
#define E_EDGES 800000
#define NBLK    98       // ceil(N_NODES / 1024)

static __device__ __forceinline__ uint packbf(float a, float b) {
  bf16 x = __float2bfloat16(a), y = __float2bfloat16(b);
  ushort ux = *reinterpret_cast<ushort*>(&x);
  ushort uy = *reinterpret_cast<ushort*>(&y);
  return (uint)ux | ((uint)uy << 16);
}
static __device__ __forceinline__ float lo16(uint u) { return __uint_as_float(u << 16); }
static __device__ __forceinline__ float hi16(uint u) { return __uint_as_float(u & 0xffff0000u); }

// ---------------- CSR build (by destination), shared by both layers ----------------
__global__ void hist2_k(const int* __restrict__ dst0, const int* __restrict__ dst1,
                        int* deg0, int* deg1) {
  int i = blockIdx.x * 256 + threadIdx.x;
  if (i < E_EDGES) {
    atomicAdd(&deg0[dst0[i]], 1);
    atomicAdd(&deg1[dst1[i]], 1);
  }
}

// multi-block scan, pass 1: per-block inclusive scan -> exclusive local, block sums
__global__ void scan_blk_k(const int* __restrict__ deg0, const int* __restrict__ deg1,
                           int* rp0, int* rp1, int* bsum) {
  __shared__ int s[1024];
  int r = blockIdx.y;
  const int* deg = r ? deg1 : deg0;
  int* rp = r ? rp1 : rp0;
  int i = blockIdx.x * 1024 + threadIdx.x;
  int v = (i < N_NODES) ? deg[i] : 0;
  s[threadIdx.x] = v;
  __syncthreads();
  for (int off = 1; off < 1024; off <<= 1) {
    int t = (threadIdx.x >= off) ? s[threadIdx.x - off] : 0;
    __syncthreads();
    s[threadIdx.x] += t;
    __syncthreads();
  }
  if (i < N_NODES) rp[i] = s[threadIdx.x] - v;   // block-local exclusive
  if (threadIdx.x == 1023) bsum[r * NBLK + blockIdx.x] = s[1023];
}

// pass 2: scan the 98 block sums per relation (2 blocks x 128 thr)
__global__ void scan_top_k(int* bsum, int* rp0, int* rp1) {
  __shared__ int s[128];
  int r = blockIdx.x;
  int v = (threadIdx.x < NBLK) ? bsum[r * NBLK + threadIdx.x] : 0;
  s[threadIdx.x] = v;
  __syncthreads();
  for (int off = 1; off < 128; off <<= 1) {
    int t = (threadIdx.x >= off) ? s[threadIdx.x - off] : 0;
    __syncthreads();
    s[threadIdx.x] += t;
    __syncthreads();
  }
  if (threadIdx.x < NBLK) bsum[r * NBLK + threadIdx.x] = s[threadIdx.x] - v;  // exclusive
  if (threadIdx.x == 127) (r ? rp1 : rp0)[N_NODES] = s[127];
}

// pass 3: add block offsets; also init fill arrays
__global__ void scan_add_k(const int* __restrict__ bsum,
                           int* rp0, int* rp1, int* fi0, int* fi1) {
  int r = blockIdx.y;
  int i = blockIdx.x * 1024 + threadIdx.x;
  if (i >= N_NODES) return;
  int* rp = r ? rp1 : rp0;
  int* fi = r ? fi1 : fi0;
  int val = rp[i] + bsum[r * NBLK + blockIdx.x];
  rp[i] = val;
  fi[i] = val;
}

// col stores the SOURCE node id directly
__global__ void scat2_k(const int* __restrict__ src0, const int* __restrict__ dst0,
                        const int* __restrict__ src1, const int* __restrict__ dst1,
                        int* fill0, int* fill1, int* cs0, int* cs1) {
  int i = blockIdx.x * 256 + threadIdx.x;
  if (i < E_EDGES) {
    int p0 = atomicAdd(&fill0[dst0[i]], 1); cs0[p0] = src0[i];
    int p1 = atomicAdd(&fill1[dst1[i]], 1); cs1[p1] = src1[i];
  }
}

// ---------------- layer-1 transform (K=2), scalar, writes XLR[node][256] bf16 ----------------
__global__ void t1_k(const float* __restrict__ x,
                     const float* __restrict__ Wl, const float* __restrict__ blp,
                     const float* __restrict__ Wr, const float* __restrict__ brp,
                     bf16* __restrict__ XLR) {
  int t = threadIdx.x;
  int node = blockIdx.x * 2 + (t >> 7);
  if (node >= N_NODES) return;
  int qq = t & 127;
  int side = qq >> 6;
  int p = qq & 63;
  int c0 = 2 * p;
  const float* W = side ? Wr : Wl;   // [2][128] k-major
  const float* B = side ? brp : blp;
  float x0 = x[node * 2], x1 = x[node * 2 + 1];
  float v0 = B[c0]     + x0 * W[c0]     + x1 * W[128 + c0];
  float v1 = B[c0 + 1] + x0 * W[c0 + 1] + x1 * W[128 + c0 + 1];
  *(uint*)(XLR + (size_t)node * 256 + side * 128 + c0) = packbf(v0, v1);
}

// ---------------- layer-2 weight prep: WT[rel][c=0..255][k=0..63] bf16 (transposed) ----------------
__global__ void wprep_k(const float* __restrict__ Wl, const float* __restrict__ Wr,
                        short* __restrict__ WT) {
  int id2 = blockIdx.x * 256 + threadIdx.x;   // 32768 = 2 rel x 256 c x 64 k
  int rel = id2 >> 14;
  int id = id2 & 16383;
  int c = id >> 6, k = id & 63;
  const float* W = (c < 128) ? (Wl + rel * 8192) : (Wr + rel * 8192);
  int cc = c & 127;
  bf16 b = __float2bfloat16(W[k * 128 + cc]);
  WT[rel * 16384 + c * 64 + k] = *reinterpret_cast<short*>(&b);
}

// ---------------- layer-2 transform: XLR[N][256] = HB[N][64] @ WT^T, MFMA 16x16x32 ----------------
__global__ __launch_bounds__(256) void mfma_t_k(const bf16* __restrict__ HB,
                                                const short* __restrict__ WT,
                                                const float* __restrict__ bl,
                                                const float* __restrict__ br,
                                                bf16* __restrict__ XLR) {
  __shared__ short sW[256 * 72];
  int t = threadIdx.x;
#pragma unroll
  for (int i = 0; i < 8; ++i) {
    int chunk = t + i * 256;                 // 2048 chunks of 8 shorts
    int c = chunk >> 3, off = (chunk & 7) * 8;
    *(short8*)(&sW[c * 72 + off]) = *(const short8*)(WT + chunk * 8);
  }
  __syncthreads();
  int wave = t >> 6, lane = t & 63;
  int q = lane >> 4, m = lane & 15;
  int rowbase = blockIdx.x * 128 + wave * 32;
  short8 afr[2][2];
#pragma unroll
  for (int rt = 0; rt < 2; ++rt)
#pragma unroll
    for (int kh = 0; kh < 2; ++kh) {
      size_t row = (size_t)(rowbase + rt * 16 + m);
      afr[rt][kh] = *(const short8*)((const short*)HB + row * 64 + kh * 32 + q * 8);
    }
  for (int ct = 0; ct < 16; ++ct) {
    int col = ct * 16 + m;
    short8 b0 = *(const short8*)(&sW[col * 72 + q * 8]);
    short8 b1 = *(const short8*)(&sW[col * 72 + 32 + q * 8]);
    float bias = (col < 128) ? bl[col] : br[col - 128];
#pragma unroll
    for (int rt = 0; rt < 2; ++rt) {
      floatx4 acc = {0.f, 0.f, 0.f, 0.f};
      acc = __builtin_amdgcn_mfma_f32_16x16x32_bf16(afr[rt][0], b0, acc, 0, 0, 0);
      acc = __builtin_amdgcn_mfma_f32_16x16x32_bf16(afr[rt][1], b1, acc, 0, 0, 0);
      int r0 = rowbase + rt * 16 + q * 4;    // C/D: col=lane&15, row=q*4+reg
#pragma unroll
      for (int i2 = 0; i2 < 4; ++i2) {
        int row = r0 + i2;
        if (row < N_NODES)
          XLR[(size_t)row * 256 + col] = __float2bfloat16(acc[i2] + bias);
      }
    }
  }
}

// ---------------- per-dst fused scores+softmax+agg, HALF-WAVE version ----------------
// wave = 1 node; lanes 0..31 process even edges, 32..63 odd edges.
// lane (l = lane&31) covers channels 4l..4l+3 (head = l>>4) via one b64 gather.
// score reduce: 4 shfls within 16-lane head groups; halves combine post-loop.
struct EdgeAcc { float a0, a1, a2, a3, den; };

static __device__ __forceinline__ void edge_step(
    uint2 u, float xr0, float xr1, float xr2, float xr3,
    float at0, float at1, float at2, float at3, EdgeAcc& A) {
  float x0 = lo16(u.x), x1 = hi16(u.x), x2 = lo16(u.y), x3 = hi16(u.y);
  float e0 = x0 + xr0; e0 = e0 > 0.f ? e0 : 0.2f * e0;
  float e1 = x1 + xr1; e1 = e1 > 0.f ? e1 : 0.2f * e1;
  float e2 = x2 + xr2; e2 = e2 > 0.f ? e2 : 0.2f * e2;
  float e3 = x3 + xr3; e3 = e3 > 0.f ? e3 : 0.2f * e3;
  float p = e0 * at0 + e1 * at1 + e2 * at2 + e3 * at3;
  p += __shfl_xor(p, 1);
  p += __shfl_xor(p, 2);
  p += __shfl_xor(p, 4);
  p += __shfl_xor(p, 8);        // 16-lane head-group total
  float ex = __expf(p);
  A.den += ex;
  A.a0 += ex * x0; A.a1 += ex * x1; A.a2 += ex * x2; A.a3 += ex * x3;
}

__global__ __launch_bounds__(256) void aggh_k(
    const int* __restrict__ rp, const int* __restrict__ cs,
    const bf16* __restrict__ X, const float* __restrict__ att,
    const float* __restrict__ bias, float* __restrict__ accum,
    uint2* __restrict__ hout, float* __restrict__ outf, int phase, int do_relu) {
  int d = (blockIdx.x * 256 + threadIdx.x) >> 6;
  int lane = threadIdx.x & 63;
  if (d >= N_NODES) return;
  int half = lane >> 5;
  int l = lane & 31;
  const float* at = att + 4 * l;
  float at0 = at[0], at1 = at[1], at2 = at[2], at3 = at[3];
  uint2 ur = *(const uint2*)(X + (size_t)d * 256 + 128 + 4 * l);
  float xr0 = lo16(ur.x), xr1 = hi16(ur.x), xr2 = lo16(ur.y), xr3 = hi16(ur.y);
  EdgeAcc A = {0.f, 0.f, 0.f, 0.f, 0.f};
  int beg = rp[d], end = rp[d + 1];
  int j = beg + half;
  // unroll-2: two independent gathers + score chains in flight
  for (; j + 2 < end; j += 4) {
    int sA = cs[j], sB = cs[j + 2];
    uint2 uA = *(const uint2*)(X + (size_t)sA * 256 + 4 * l);
    uint2 uB = *(const uint2*)(X + (size_t)sB * 256 + 4 * l);
    edge_step(uA, xr0, xr1, xr2, xr3, at0, at1, at2, at3, A);
    edge_step(uB, xr0, xr1, xr2, xr3, at0, at1, at2, at3, A);
  }
  for (; j < end; j += 2) {
    int s = cs[j];
    uint2 u = *(const uint2*)(X + (size_t)s * 256 + 4 * l);
    edge_step(u, xr0, xr1, xr2, xr3, at0, at1, at2, at3, A);
  }
  // combine edge-parity halves
  A.den += __shfl_xor(A.den, 32);
  A.a0 += __shfl_xor(A.a0, 32);
  A.a1 += __shfl_xor(A.a1, 32);
  A.a2 += __shfl_xor(A.a2, 32);
  A.a3 += __shfl_xor(A.a3, 32);
  float inv = 1.f / (A.den + 1e-16f);   // per-head (lanes 0..15 h0, 16..31 h1)
  A.a0 *= inv; A.a1 *= inv; A.a2 *= inv; A.a3 *= inv;
  // head mean: lane l (<16, ch 4l+i of h0) pairs with lane l+16 (same ch of h1)
  float o0 = 0.5f * (A.a0 + __shfl_xor(A.a0, 16));
  float o1 = 0.5f * (A.a1 + __shfl_xor(A.a1, 16));
  float o2 = 0.5f * (A.a2 + __shfl_xor(A.a2, 16));
  float o3 = 0.5f * (A.a3 + __shfl_xor(A.a3, 16));
  if (lane < 16) {
    int c0 = 4 * lane;
    o0 += bias[c0]; o1 += bias[c0 + 1]; o2 += bias[c0 + 2]; o3 += bias[c0 + 3];
    size_t oi = (size_t)d * 64 + c0;
    if (phase == 0) {
      *(float4*)(accum + oi) = make_float4(o0, o1, o2, o3);
    } else {
      float4 pa = *(const float4*)(accum + oi);
      float v0 = 0.5f * (pa.x + o0);
      float v1 = 0.5f * (pa.y + o1);
      float v2 = 0.5f * (pa.z + o2);
      float v3 = 0.5f * (pa.w + o3);
      if (do_relu) {
        v0 = fmaxf(v0, 0.f); v1 = fmaxf(v1, 0.f);
        v2 = fmaxf(v2, 0.f); v3 = fmaxf(v3, 0.f);
      }
      if (outf) *(float4*)(outf + oi) = make_float4(v0, v1, v2, v3);
      else hout[(size_t)d * 16 + lane] = make_uint2(packbf(v0, v1), packbf(v2, v3));
    }
  }
}

extern "C" void kernel_launch(void* const* d_in, const int* in_sizes, int n_in,
                              void* d_out, int out_size, void* d_ws, size_t ws_size,
                              hipStream_t stream) {
  const float* x       = (const float*)d_in[0];
  const int*   e_adj   = (const int*)d_in[1];
  const int*   e_ray   = (const int*)d_in[2];
  const float* l1_Wl   = (const float*)d_in[3];
  const float* l1_bl   = (const float*)d_in[4];
  const float* l1_Wr   = (const float*)d_in[5];
  const float* l1_br   = (const float*)d_in[6];
  const float* l1_att  = (const float*)d_in[7];
  const float* l1_bias = (const float*)d_in[8];
  const float* l2_Wl   = (const float*)d_in[9];
  const float* l2_bl   = (const float*)d_in[10];
  const float* l2_Wr   = (const float*)d_in[11];
  const float* l2_br   = (const float*)d_in[12];
  const float* l2_att  = (const float*)d_in[13];
  const float* l2_bias = (const float*)d_in[14];
  float* out = (float*)d_out;

  // workspace (~74 MB)
  char* w = (char*)d_ws;
  size_t off = 0;
  auto alloc = [&](size_t bytes) -> char* {
    char* p = w + off;
    off += (bytes + 255) & ~(size_t)255;
    return p;
  };
  bf16* XLR  = (bf16*)alloc((size_t)N_PAD * 256 * 2);   // 51.2 MB
  bf16* HB   = (bf16*)alloc((size_t)N_PAD * 64 * 2);    // 12.8 MB
  short* WT  = (short*)alloc(2 * 16384 * 2);            // 64 KB
  int* RP0   = (int*)alloc((size_t)(N_NODES + 1) * 4);
  int* RP1   = (int*)alloc((size_t)(N_NODES + 1) * 4);
  int* FI0   = (int*)alloc((size_t)N_NODES * 4);
  int* FI1   = (int*)alloc((size_t)N_NODES * 4);
  int* CS0   = (int*)alloc((size_t)E_EDGES * 4);
  int* CS1   = (int*)alloc((size_t)E_EDGES * 4);
  int* DG0   = (int*)alloc((size_t)N_NODES * 4);
  int* DG1   = (int*)alloc((size_t)N_NODES * 4);
  int* BSUM  = (int*)alloc(2 * NBLK * 4);
  float* ACC = out;  // relation-0 partial; phase-1 reads before writing same index

  const int* src_adj = e_adj;
  const int* dst_adj = e_adj + E_EDGES;
  const int* src_ray = e_ray;
  const int* dst_ray = e_ray + E_EDGES;

  const int EB  = (E_EDGES + 255) / 256;   // 3125
  const int WNB = (N_NODES * 64) / 256;    // 25000 (one wave per node)
  const int TNB = (N_NODES + 1) / 2;       // 50000
  const int MB  = N_PAD / 128;             // 782

  // CSR build (multi-block scan)
  hipMemsetAsync(DG0, 0, (size_t)N_NODES * 4, stream);
  hipMemsetAsync(DG1, 0, (size_t)N_NODES * 4, stream);
  hist2_k<<<EB, 256, 0, stream>>>(dst_adj, dst_ray, DG0, DG1);
  scan_blk_k<<<dim3(NBLK, 2), 1024, 0, stream>>>(DG0, DG1, RP0, RP1, BSUM);
  scan_top_k<<<2, 128, 0, stream>>>(BSUM, RP0, RP1);
  scan_add_k<<<dim3(NBLK, 2), 1024, 0, stream>>>(BSUM, RP0, RP1, FI0, FI1);
  scat2_k<<<EB, 256, 0, stream>>>(src_adj, dst_adj, src_ray, dst_ray, FI0, FI1, CS0, CS1);
  wprep_k<<<128, 256, 0, stream>>>(l2_Wl, l2_Wr, WT);

  // ---- layer 1 (K=2), relu, hidden -> HB (bf16) ----
  for (int r = 0; r < 2; ++r) {
    const int* rp = r ? RP1 : RP0;
    const int* cs = r ? CS1 : CS0;
    t1_k<<<TNB, 256, 0, stream>>>(x, l1_Wl + r * 256, l1_bl + r * 128,
                                  l1_Wr + r * 256, l1_br + r * 128, XLR);
    aggh_k<<<WNB, 256, 0, stream>>>(rp, cs, XLR, l1_att + r * 128, l1_bias + r * 64,
                                    ACC, (uint2*)HB, nullptr, r, 1);
  }

  // ---- layer 2 (K=64, MFMA), writes fp32 output ----
  for (int r = 0; r < 2; ++r) {
    const int* rp = r ? RP1 : RP0;
    const int* cs = r ? CS1 : CS0;
    mfma_t_k<<<MB, 256, 0, stream>>>(HB, WT + r * 16384,
                                     l2_bl + r * 128, l2_br + r * 128, XLR);
    aggh_k<<<WNB, 256, 0, stream>>>(rp, cs, XLR, l2_att + r * 128, l2_bias + r * 64,
                                    ACC, nullptr, out, r, 0);
  }
}

// Round 6
// 585.372 us; speedup vs baseline: 3.5534x; 1.1010x over previous
//
#include <hip/hip_runtime.h>
#include <hip/hip_bf16.h>

typedef __hip_bfloat16 bf16;
typedef unsigned int uint;
typedef unsigned short ushort;
typedef __attribute__((ext_vector_type(8))) short short8;  // 8 x bf16 (4 VGPRs)
typedef __attribute__((ext_vector_type(4))) float floatx4;

#define N_NODES 100000
#define N_PAD   100096   // multiple of 128 for the MFMA row tiling
#define E_EDGES 800000
#define NBLK    98       // ceil(N_NODES / 1024)
#define NSLICE  8        // one dst-slice per XCD (blockIdx % 8 ~ XCD id)
#define SLICE_N 12512    // ceil(N_NODES / NSLICE)
#define SLICE_BLOCKS 512 // blocks per slice row

static __device__ __forceinline__ uint packbf(float a, float b) {
  bf16 x = __float2bfloat16(a), y = __float2bfloat16(b);
  ushort ux = *reinterpret_cast<ushort*>(&x);
  ushort uy = *reinterpret_cast<ushort*>(&y);
  return (uint)ux | ((uint)uy << 16);
}
static __device__ __forceinline__ float lo16(uint u) { return __uint_as_float(u << 16); }
static __device__ __forceinline__ float hi16(uint u) { return __uint_as_float(u & 0xffff0000u); }

// ---------------- CSR build (by destination), XCD-sliced ----------------
// slice = blockIdx.x & 7 rides the round-robin workgroup->XCD dispatch so each
// 400 KB dst-slice of DG/FI/CS is touched by (mostly) one XCD's L2 -> writes
// coalesce in-cache instead of evicting near-empty 64B lines to HBM.
// Correctness does NOT depend on the mapping (pure predicate per slice).
__global__ void hist_sliced_k(const int* __restrict__ dst0, const int* __restrict__ dst1,
                              int* dg0, int* dg1) {
  int slice = blockIdx.x & (NSLICE - 1);
  int blk = blockIdx.x >> 3;
  int lo = slice * SLICE_N, hi = lo + SLICE_N;
  for (int i = blk * 256 + threadIdx.x; i < E_EDGES; i += SLICE_BLOCKS * 256) {
    int d0 = dst0[i];
    if (d0 >= lo && d0 < hi) atomicAdd(&dg0[d0], 1);
    int d1 = dst1[i];
    if (d1 >= lo && d1 < hi) atomicAdd(&dg1[d1], 1);
  }
}

__global__ void scat_sliced_k(const int* __restrict__ src0, const int* __restrict__ dst0,
                              const int* __restrict__ src1, const int* __restrict__ dst1,
                              int* fi0, int* fi1, int* cs0, int* cs1) {
  int slice = blockIdx.x & (NSLICE - 1);
  int blk = blockIdx.x >> 3;
  int lo = slice * SLICE_N, hi = lo + SLICE_N;
  for (int i = blk * 256 + threadIdx.x; i < E_EDGES; i += SLICE_BLOCKS * 256) {
    int d0 = dst0[i];
    if (d0 >= lo && d0 < hi) { int p = atomicAdd(&fi0[d0], 1); cs0[p] = src0[i]; }
    int d1 = dst1[i];
    if (d1 >= lo && d1 < hi) { int p = atomicAdd(&fi1[d1], 1); cs1[p] = src1[i]; }
  }
}

// multi-block scan, pass 1: per-block inclusive scan -> exclusive local, block sums
__global__ void scan_blk_k(const int* __restrict__ deg0, const int* __restrict__ deg1,
                           int* rp0, int* rp1, int* bsum) {
  __shared__ int s[1024];
  int r = blockIdx.y;
  const int* deg = r ? deg1 : deg0;
  int* rp = r ? rp1 : rp0;
  int i = blockIdx.x * 1024 + threadIdx.x;
  int v = (i < N_NODES) ? deg[i] : 0;
  s[threadIdx.x] = v;
  __syncthreads();
  for (int off = 1; off < 1024; off <<= 1) {
    int t = (threadIdx.x >= off) ? s[threadIdx.x - off] : 0;
    __syncthreads();
    s[threadIdx.x] += t;
    __syncthreads();
  }
  if (i < N_NODES) rp[i] = s[threadIdx.x] - v;   // block-local exclusive
  if (threadIdx.x == 1023) bsum[r * NBLK + blockIdx.x] = s[1023];
}

// pass 2: scan the 98 block sums per relation
__global__ void scan_top_k(int* bsum, int* rp0, int* rp1) {
  __shared__ int s[128];
  int r = blockIdx.x;
  int v = (threadIdx.x < NBLK) ? bsum[r * NBLK + threadIdx.x] : 0;
  s[threadIdx.x] = v;
  __syncthreads();
  for (int off = 1; off < 128; off <<= 1) {
    int t = (threadIdx.x >= off) ? s[threadIdx.x - off] : 0;
    __syncthreads();
    s[threadIdx.x] += t;
    __syncthreads();
  }
  if (threadIdx.x < NBLK) bsum[r * NBLK + threadIdx.x] = s[threadIdx.x] - v;  // exclusive
  if (threadIdx.x == 127) (r ? rp1 : rp0)[N_NODES] = s[127];
}

// pass 3: add block offsets; also init fill arrays
__global__ void scan_add_k(const int* __restrict__ bsum,
                           int* rp0, int* rp1, int* fi0, int* fi1) {
  int r = blockIdx.y;
  int i = blockIdx.x * 1024 + threadIdx.x;
  if (i >= N_NODES) return;
  int* rp = r ? rp1 : rp0;
  int* fi = r ? fi1 : fi0;
  int val = rp[i] + bsum[r * NBLK + blockIdx.x];
  rp[i] = val;
  fi[i] = val;
}

// ---------------- layer-1 transform (K=2), scalar, writes XL/XR [node][128] bf16 ----------------
__global__ void t1_k(const float* __restrict__ x,
                     const float* __restrict__ Wl, const float* __restrict__ blp,
                     const float* __restrict__ Wr, const float* __restrict__ brp,
                     bf16* __restrict__ XL, bf16* __restrict__ XR) {
  int t = threadIdx.x;
  int node = blockIdx.x * 2 + (t >> 7);
  if (node >= N_NODES) return;
  int qq = t & 127;
  int side = qq >> 6;
  int p = qq & 63;
  int c0 = 2 * p;
  const float* W = side ? Wr : Wl;   // [2][128] k-major
  const float* B = side ? brp : blp;
  bf16* X = side ? XR : XL;
  float x0 = x[node * 2], x1 = x[node * 2 + 1];
  float v0 = B[c0]     + x0 * W[c0]     + x1 * W[128 + c0];
  float v1 = B[c0 + 1] + x0 * W[c0 + 1] + x1 * W[128 + c0 + 1];
  *(uint*)(X + (size_t)node * 128 + c0) = packbf(v0, v1);
}

// ---------------- layer-2 weight prep: WT[rel][c=0..255][k=0..63] bf16 (transposed) ----------------
__global__ void wprep_k(const float* __restrict__ Wl, const float* __restrict__ Wr,
                        short* __restrict__ WT) {
  int id2 = blockIdx.x * 256 + threadIdx.x;   // 32768 = 2 rel x 256 c x 64 k
  int rel = id2 >> 14;
  int id = id2 & 16383;
  int c = id >> 6, k = id & 63;
  const float* W = (c < 128) ? (Wl + rel * 8192) : (Wr + rel * 8192);
  int cc = c & 127;
  bf16 b = __float2bfloat16(W[k * 128 + cc]);
  WT[rel * 16384 + c * 64 + k] = *reinterpret_cast<short*>(&b);
}

// ---------------- layer-2 transform: XL/XR = HB @ WT^T, MFMA 16x16x32 ----------------
__global__ __launch_bounds__(256) void mfma_t_k(const bf16* __restrict__ HB,
                                                const short* __restrict__ WT,
                                                const float* __restrict__ bl,
                                                const float* __restrict__ br,
                                                bf16* __restrict__ XL,
                                                bf16* __restrict__ XR) {
  __shared__ short sW[256 * 72];
  int t = threadIdx.x;
#pragma unroll
  for (int i = 0; i < 8; ++i) {
    int chunk = t + i * 256;                 // 2048 chunks of 8 shorts
    int c = chunk >> 3, off = (chunk & 7) * 8;
    *(short8*)(&sW[c * 72 + off]) = *(const short8*)(WT + chunk * 8);
  }
  __syncthreads();
  int wave = t >> 6, lane = t & 63;
  int q = lane >> 4, m = lane & 15;
  int rowbase = blockIdx.x * 128 + wave * 32;
  short8 afr[2][2];
#pragma unroll
  for (int rt = 0; rt < 2; ++rt)
#pragma unroll
    for (int kh = 0; kh < 2; ++kh) {
      size_t row = (size_t)(rowbase + rt * 16 + m);
      afr[rt][kh] = *(const short8*)((const short*)HB + row * 64 + kh * 32 + q * 8);
    }
  for (int ct = 0; ct < 16; ++ct) {
    int col = ct * 16 + m;
    short8 b0 = *(const short8*)(&sW[col * 72 + q * 8]);
    short8 b1 = *(const short8*)(&sW[col * 72 + 32 + q * 8]);
    float bias = (col < 128) ? bl[col] : br[col - 128];
    bf16* X = (col < 128) ? XL : XR;       // wave-uniform per ct (ct<8 -> XL)
    int c128 = col & 127;
#pragma unroll
    for (int rt = 0; rt < 2; ++rt) {
      floatx4 acc = {0.f, 0.f, 0.f, 0.f};
      acc = __builtin_amdgcn_mfma_f32_16x16x32_bf16(afr[rt][0], b0, acc, 0, 0, 0);
      acc = __builtin_amdgcn_mfma_f32_16x16x32_bf16(afr[rt][1], b1, acc, 0, 0, 0);
      int r0 = rowbase + rt * 16 + q * 4;    // C/D: col=lane&15, row=q*4+reg
#pragma unroll
      for (int i2 = 0; i2 < 4; ++i2) {
        int row = r0 + i2;
        if (row < N_NODES)
          X[(size_t)row * 128 + c128] = __float2bfloat16(acc[i2] + bias);
      }
    }
  }
}

// ---------------- per-dst fused scores+softmax+agg, half-wave ----------------
struct EdgeAcc { float a0, a1, a2, a3, den; };

static __device__ __forceinline__ void edge_step(
    uint2 u, float xr0, float xr1, float xr2, float xr3,
    float at0, float at1, float at2, float at3, EdgeAcc& A) {
  float x0 = lo16(u.x), x1 = hi16(u.x), x2 = lo16(u.y), x3 = hi16(u.y);
  float e0 = x0 + xr0; e0 = e0 > 0.f ? e0 : 0.2f * e0;
  float e1 = x1 + xr1; e1 = e1 > 0.f ? e1 : 0.2f * e1;
  float e2 = x2 + xr2; e2 = e2 > 0.f ? e2 : 0.2f * e2;
  float e3 = x3 + xr3; e3 = e3 > 0.f ? e3 : 0.2f * e3;
  float p = e0 * at0 + e1 * at1 + e2 * at2 + e3 * at3;
  p += __shfl_xor(p, 1);
  p += __shfl_xor(p, 2);
  p += __shfl_xor(p, 4);
  p += __shfl_xor(p, 8);        // 16-lane head-group total
  float ex = __expf(p);
  A.den += ex;
  A.a0 += ex * x0; A.a1 += ex * x1; A.a2 += ex * x2; A.a3 += ex * x3;
}

__global__ __launch_bounds__(256) void aggh_k(
    const int* __restrict__ rp, const int* __restrict__ cs,
    const bf16* __restrict__ XL, const bf16* __restrict__ XR,
    const float* __restrict__ att, const float* __restrict__ bias,
    float* __restrict__ accum, uint2* __restrict__ hout,
    float* __restrict__ outf, int phase, int do_relu) {
  int d = (blockIdx.x * 256 + threadIdx.x) >> 6;
  int lane = threadIdx.x & 63;
  if (d >= N_NODES) return;
  int half = lane >> 5;
  int l = lane & 31;
  const float* at = att + 4 * l;
  float at0 = at[0], at1 = at[1], at2 = at[2], at3 = at[3];
  uint2 ur = *(const uint2*)(XR + (size_t)d * 128 + 4 * l);
  float xr0 = lo16(ur.x), xr1 = hi16(ur.x), xr2 = lo16(ur.y), xr3 = hi16(ur.y);
  EdgeAcc A = {0.f, 0.f, 0.f, 0.f, 0.f};
  int beg = rp[d], end = rp[d + 1];
  int j = beg + half;
  for (; j + 2 < end; j += 4) {
    int sA = cs[j], sB = cs[j + 2];
    uint2 uA = *(const uint2*)(XL + (size_t)sA * 128 + 4 * l);
    uint2 uB = *(const uint2*)(XL + (size_t)sB * 128 + 4 * l);
    edge_step(uA, xr0, xr1, xr2, xr3, at0, at1, at2, at3, A);
    edge_step(uB, xr0, xr1, xr2, xr3, at0, at1, at2, at3, A);
  }
  for (; j < end; j += 2) {
    int s = cs[j];
    uint2 u = *(const uint2*)(XL + (size_t)s * 128 + 4 * l);
    edge_step(u, xr0, xr1, xr2, xr3, at0, at1, at2, at3, A);
  }
  // combine edge-parity halves
  A.den += __shfl_xor(A.den, 32);
  A.a0 += __shfl_xor(A.a0, 32);
  A.a1 += __shfl_xor(A.a1, 32);
  A.a2 += __shfl_xor(A.a2, 32);
  A.a3 += __shfl_xor(A.a3, 32);
  float inv = 1.f / (A.den + 1e-16f);   // per-head (lanes 0..15 h0, 16..31 h1)
  A.a0 *= inv; A.a1 *= inv; A.a2 *= inv; A.a3 *= inv;
  // head mean: lane l (<16, ch 4l+i of h0) pairs with lane l+16 (same ch of h1)
  float o0 = 0.5f * (A.a0 + __shfl_xor(A.a0, 16));
  float o1 = 0.5f * (A.a1 + __shfl_xor(A.a1, 16));
  float o2 = 0.5f * (A.a2 + __shfl_xor(A.a2, 16));
  float o3 = 0.5f * (A.a3 + __shfl_xor(A.a3, 16));
  if (lane < 16) {
    int c0 = 4 * lane;
    o0 += bias[c0]; o1 += bias[c0 + 1]; o2 += bias[c0 + 2]; o3 += bias[c0 + 3];
    size_t oi = (size_t)d * 64 + c0;
    if (phase == 0) {
      *(float4*)(accum + oi) = make_float4(o0, o1, o2, o3);
    } else {
      float4 pa = *(const float4*)(accum + oi);
      float v0 = 0.5f * (pa.x + o0);
      float v1 = 0.5f * (pa.y + o1);
      float v2 = 0.5f * (pa.z + o2);
      float v3 = 0.5f * (pa.w + o3);
      if (do_relu) {
        v0 = fmaxf(v0, 0.f); v1 = fmaxf(v1, 0.f);
        v2 = fmaxf(v2, 0.f); v3 = fmaxf(v3, 0.f);
      }
      if (outf) *(float4*)(outf + oi) = make_float4(v0, v1, v2, v3);
      else hout[(size_t)d * 16 + lane] = make_uint2(packbf(v0, v1), packbf(v2, v3));
    }
  }
}

extern "C" void kernel_launch(void* const* d_in, const int* in_sizes, int n_in,
                              void* d_out, int out_size, void* d_ws, size_t ws_size,
                              hipStream_t stream) {
  const float* x       = (const float*)d_in[0];
  const int*   e_adj   = (const int*)d_in[1];
  const int*   e_ray   = (const int*)d_in[2];
  const float* l1_Wl   = (const float*)d_in[3];
  const float* l1_bl   = (const float*)d_in[4];
  const float* l1_Wr   = (const float*)d_in[5];
  const float* l1_br   = (const float*)d_in[6];
  const float* l1_att  = (const float*)d_in[7];
  const float* l1_bias = (const float*)d_in[8];
  const float* l2_Wl   = (const float*)d_in[9];
  const float* l2_bl   = (const float*)d_in[10];
  const float* l2_Wr   = (const float*)d_in[11];
  const float* l2_br   = (const float*)d_in[12];
  const float* l2_att  = (const float*)d_in[13];
  const float* l2_bias = (const float*)d_in[14];
  float* out = (float*)d_out;

  // workspace (~74 MB)
  char* w = (char*)d_ws;
  size_t off = 0;
  auto alloc = [&](size_t bytes) -> char* {
    char* p = w + off;
    off += (bytes + 255) & ~(size_t)255;
    return p;
  };
  bf16* XL   = (bf16*)alloc((size_t)N_PAD * 128 * 2);   // 25.6 MB
  bf16* XR   = (bf16*)alloc((size_t)N_PAD * 128 * 2);   // 25.6 MB
  bf16* HB   = (bf16*)alloc((size_t)N_PAD * 64 * 2);    // 12.8 MB
  short* WT  = (short*)alloc(2 * 16384 * 2);            // 64 KB
  int* RP0   = (int*)alloc((size_t)(N_NODES + 1) * 4);
  int* RP1   = (int*)alloc((size_t)(N_NODES + 1) * 4);
  int* FI0   = (int*)alloc((size_t)N_NODES * 4);
  int* FI1   = (int*)alloc((size_t)N_NODES * 4);
  int* CS0   = (int*)alloc((size_t)E_EDGES * 4);
  int* CS1   = (int*)alloc((size_t)E_EDGES * 4);
  int* DG0   = (int*)alloc((size_t)N_NODES * 4);
  int* DG1   = (int*)alloc((size_t)N_NODES * 4);
  int* BSUM  = (int*)alloc(2 * NBLK * 4);
  float* ACC = out;  // relation-0 partial; phase-1 reads before writing same index

  const int* src_adj = e_adj;
  const int* dst_adj = e_adj + E_EDGES;
  const int* src_ray = e_ray;
  const int* dst_ray = e_ray + E_EDGES;

  const int WNB = (N_NODES * 64) / 256;    // 25000 (one wave per node)
  const int TNB = (N_NODES + 1) / 2;       // 50000
  const int MB  = N_PAD / 128;             // 782
  const int SB  = SLICE_BLOCKS * NSLICE;   // 4096

  // CSR build (XCD-sliced hist/scatter + multi-block scan)
  hipMemsetAsync(DG0, 0, (size_t)N_NODES * 4, stream);
  hipMemsetAsync(DG1, 0, (size_t)N_NODES * 4, stream);
  hist_sliced_k<<<SB, 256, 0, stream>>>(dst_adj, dst_ray, DG0, DG1);
  scan_blk_k<<<dim3(NBLK, 2), 1024, 0, stream>>>(DG0, DG1, RP0, RP1, BSUM);
  scan_top_k<<<2, 128, 0, stream>>>(BSUM, RP0, RP1);
  scan_add_k<<<dim3(NBLK, 2), 1024, 0, stream>>>(BSUM, RP0, RP1, FI0, FI1);
  scat_sliced_k<<<SB, 256, 0, stream>>>(src_adj, dst_adj, src_ray, dst_ray,
                                        FI0, FI1, CS0, CS1);
  wprep_k<<<128, 256, 0, stream>>>(l2_Wl, l2_Wr, WT);

  // ---- layer 1 (K=2), relu, hidden -> HB (bf16) ----
  for (int r = 0; r < 2; ++r) {
    const int* rp = r ? RP1 : RP0;
    const int* cs = r ? CS1 : CS0;
    t1_k<<<TNB, 256, 0, stream>>>(x, l1_Wl + r * 256, l1_bl + r * 128,
                                  l1_Wr + r * 256, l1_br + r * 128, XL, XR);
    aggh_k<<<WNB, 256, 0, stream>>>(rp, cs, XL, XR, l1_att + r * 128, l1_bias + r * 64,
                                    ACC, (uint2*)HB, nullptr, r, 1);
  }

  // ---- layer 2 (K=64, MFMA), writes fp32 output ----
  for (int r = 0; r < 2; ++r) {
    const int* rp = r ? RP1 : RP0;
    const int* cs = r ? CS1 : CS0;
    mfma_t_k<<<MB, 256, 0, stream>>>(HB, WT + r * 16384,
                                     l2_bl + r * 128, l2_br + r * 128, XL, XR);
    aggh_k<<<WNB, 256, 0, stream>>>(rp, cs, XL, XR, l2_att + r * 128, l2_bias + r * 64,
                                    ACC, nullptr, out, r, 0);
  }
}